// Round 9
// baseline (97.754 us; speedup 1.0000x reference)
//
#include <hip/hip_runtime.h>

#define N_  128
#define C_  256
#define T_  48
#define V_  25

typedef unsigned int u32;

__device__ __forceinline__ float b2f(unsigned short u) {
    union { float f; u32 i; } c; c.i = ((u32)u) << 16; return c.f;
}
__device__ __forceinline__ unsigned short f2b(float f) {
    union { float f; u32 i; } c; c.f = f;
    u32 r = c.i + 0x7fffu + ((c.i >> 16) & 1u);   // RNE
    return (unsigned short)(r >> 16);
}

// slot->group mapping for the shifted bf16 row layout (H = alignment shift)
template<int H>
__device__ __forceinline__ void addSlot(float& s0, float& s1, float& s2, int s, float v) {
    const int m = (s < 72) ? (s + H) : ((s - 72 < H) ? (s - 72) : s);
    if (m < 25) s0 += v; else if (m < 50) s1 += v; else s2 += v;
}

template<int H>
__device__ __forceinline__ void rowMeans(const unsigned short* row, float* xo) {
    float s0 = 0.f, s1 = 0.f, s2 = 0.f;
    #pragma unroll
    for (int q = 0; q < 37; ++q) {
        u32 u = *(const u32*)(row + 2 * q);
        addSlot<H>(s0, s1, s2, 2 * q,     b2f((unsigned short)(u & 0xffffu)));
        addSlot<H>(s0, s1, s2, 2 * q + 1, b2f((unsigned short)(u >> 16)));
    }
    addSlot<H>(s0, s1, s2, 74, b2f(row[74]));
    xo[0] = s0 * 0.04f; xo[1] = s1 * 0.04f; xo[2] = s2 * 0.04f;
}

// Block = (n, quad of 4 segments). 4-tile software pipeline: tile i+1's global
// loads are issued (into registers) before tile i's compute phases and consumed
// after tile i's store phase. All weights preloaded to LDS so compute phases
// contain no vmem consumption (no early waitcnt drain of the prefetch).
__global__ __launch_bounds__(256, 4) void k_pipe(
    const float* __restrict__ x,
    const float* __restrict__ wsq, const float* __restrict__ bsq,
    const float* __restrict__ gamma, const float* __restrict__ beta,
    const float* __restrict__ rmean, const float* __restrict__ rvar,
    const float* __restrict__ wc1, const float* __restrict__ bc1,
    const float* __restrict__ wex, const float* __restrict__ bex,
    float* __restrict__ out)
{
    __shared__ unsigned short xs[256 * 78];  // bf16 tile, row stride 78
    __shared__ float wsqL[256 * 17];         // wsq transposed [c][r], pad 17
    __shared__ float wc1L[256];
    __shared__ float xb[768];                // v-means [c][t]
    __shared__ float gs[768];                // gate [c][t]; first 384 = B1 scratch
    __shared__ float ybn[48], y1[48], mv[48];
    __shared__ float scL[16], shL[16], bc1L[16];

    const int tid = threadIdx.x;
    const unsigned bid = blockIdx.x;
    const unsigned o   = (bid & 7u) * 64u + (bid >> 3);  // bijective XCD chunk swizzle
    const unsigned n   = o >> 2;
    const unsigned sq  = o & 3u;
    const int seg0     = (int)(sq * 4);                  // h(seg0+j) == j

    const float* xn = x   + (size_t)n * 307200u;
    float*       on = out + (size_t)n * 307200u;

    float4 v[18]; float ev[3];

    auto issueLoads = [&](int seg, int h) {
        const float* rowx = xn + seg * 75;
        #pragma unroll
        for (int it = 0; it < 18; ++it) {
            int j = it * 256 + tid, c = j / 18, k = j - c * 18;
            v[it] = *(const float4*)(rowx + c * 1200 + h + k * 4);
        }
        #pragma unroll
        for (int it = 0; it < 3; ++it) {
            int j = it * 256 + tid, c = j / 3, e = j - c * 3;
            int m = (e < h) ? e : e + 72;
            ev[it] = rowx[c * 1200 + m];
        }
    };
    auto convertStore = [&]() {
        #pragma unroll
        for (int it = 0; it < 18; ++it) {
            int j = it * 256 + tid, c = j / 18, k = j - c * 18;
            u32 p0 = (u32)f2b(v[it].x) | ((u32)f2b(v[it].y) << 16);
            u32 p1 = (u32)f2b(v[it].z) | ((u32)f2b(v[it].w) << 16);
            u32 s  = (u32)(c * 78 + k * 4);
            *(u32*)&xs[s]     = p0;
            *(u32*)&xs[s + 2] = p1;
        }
        #pragma unroll
        for (int it = 0; it < 3; ++it) {
            int j = it * 256 + tid, c = j / 3, e = j - c * 3;
            xs[c * 78 + 72 + e] = f2b(ev[it]);
        }
    };
    auto gateMath = [&]() {
        float* part = gs;                     // alias: consumed before gs written
        #pragma unroll
        for (int pp = 0; pp < 2; ++pp) {
            int p = pp * 256 + tid;
            if (p < 384) {
                int h8 = p / 48, q = p - h8 * 48, tt = q >> 4, r = q & 15;
                float acc = 0.f;
                #pragma unroll
                for (int i = 0; i < 32; ++i)
                    acc += xb[(h8 * 32 + i) * 3 + tt] * wsqL[(h8 * 32 + i) * 17 + r];
                part[p] = acc;
            }
        }
        __syncthreads();
        if (tid < 48) {                       // combine + folded BN
            int tt = tid >> 4, r = tid & 15;
            float acc = 0.f;
            #pragma unroll
            for (int h8 = 0; h8 < 8; ++h8) acc += part[h8 * 48 + tt * 16 + r];
            ybn[tt * 16 + r] = acc * scL[r] + shL[r];
        }
        __syncthreads();
        if (tid < 48) {                       // conv1
            int tt = tid >> 4, s = tid & 15;
            float acc = bc1L[s];
            #pragma unroll
            for (int r = 0; r < 16; ++r) acc += ybn[tt * 16 + r] * wc1L[s * 16 + r];
            y1[tt * 16 + s] = acc;
        }
        __syncthreads();
        if (tid < 48) {                       // temporal diff
            int tt = tid >> 4, r = tid & 15;
            mv[tid] = (tt < 2) ? (y1[(tt + 1) * 16 + r] - ybn[tt * 16 + r]) : 0.f;
        }
        __syncthreads();
        {                                     // expand + sigmoid (streamed wex, 1 live reg)
            float a0 = bex[tid], a1 = a0, a2 = a0;
            #pragma unroll
            for (int r = 0; r < 16; ++r) {
                float wr = wex[tid * 16 + r];
                a0 += mv[r]      * wr;
                a1 += mv[16 + r] * wr;
                a2 += mv[32 + r] * wr;
            }
            gs[tid * 3 + 0] = 1.f / (1.f + expf(-a0));
            gs[tid * 3 + 1] = 1.f / (1.f + expf(-a1));
            gs[tid * 3 + 2] = 1.f / (1.f + expf(-a2));
        }
        __syncthreads();
    };
    auto applyStore = [&](int seg, int h) {
        float* rowo = on + seg * 75;
        #pragma unroll
        for (int it = 0; it < 18; ++it) {
            int j = it * 256 + tid, c = j / 18, k = j - c * 18;
            u32 s  = (u32)(c * 78 + k * 4);
            u32 q0 = *(const u32*)&xs[s];
            u32 q1 = *(const u32*)&xs[s + 2];
            int m0 = h + k * 4;
            int t0 = (m0 * 41) >> 10;
            int rem = m0 - t0 * 25;
            float g0 = gs[c * 3 + t0];
            float g3 = gs[c * 3 + (((m0 + 3) * 41) >> 10)];
            float4 ov;
            ov.x = b2f((unsigned short)(q0 & 0xffffu)) * g0;
            ov.y = b2f((unsigned short)(q0 >> 16))     * ((rem + 1 < 25) ? g0 : g3);
            ov.z = b2f((unsigned short)(q1 & 0xffffu)) * ((rem + 2 < 25) ? g0 : g3);
            ov.w = b2f((unsigned short)(q1 >> 16))     * ((rem + 3 < 25) ? g0 : g3);
            *(float4*)(rowo + c * 1200 + h + k * 4) = ov;
        }
        #pragma unroll
        for (int it = 0; it < 3; ++it) {
            int j = it * 256 + tid, c = j / 3, e = j - c * 3;
            int m = (e < h) ? e : e + 72;
            int t = (m * 41) >> 10;
            rowo[c * 1200 + m] = b2f(xs[c * 78 + 72 + e]) * gs[c * 3 + t];
        }
    };

    // ---- prologue: first tile loads + weight preload ----
    issueLoads(seg0, 0);
    {
        #pragma unroll
        for (int it = 0; it < 16; ++it) {     // wsq -> transposed LDS
            int j = it * 256 + tid;
            int r = j >> 8, c = j & 255;
            wsqL[c * 17 + r] = wsq[j];
        }
        wc1L[tid] = wc1[tid];
        if (tid < 16) {
            float sc = gamma[tid] * rsqrtf(rvar[tid] + 1e-5f);
            scL[tid] = sc;
            shL[tid] = (beta[tid] - rmean[tid] * sc) + bsq[tid] * sc;   // bsq folded
            bc1L[tid] = bc1[tid];
        }
    }
    convertStore();
    __syncthreads();

    // ---- 4-tile pipeline; h(seg0+j) == j (compile-time after unroll) ----
    #pragma unroll
    for (int j = 0; j < 4; ++j) {
        const int seg = seg0 + j;
        if (j < 3) issueLoads(seg + 1, j + 1);      // prefetch next tile
        __builtin_amdgcn_sched_barrier(0);          // pin: loads must not sink
        {
            const unsigned short* row = xs + tid * 78;
            float* xo = xb + tid * 3;
            if      (j == 0) rowMeans<0>(row, xo);
            else if (j == 1) rowMeans<1>(row, xo);
            else if (j == 2) rowMeans<2>(row, xo);
            else             rowMeans<3>(row, xo);
        }
        __syncthreads();
        gateMath();
        applyStore(seg, j);
        __syncthreads();
        if (j < 3) { convertStore(); __syncthreads(); }
    }
}

extern "C" void kernel_launch(void* const* d_in, const int* in_sizes, int n_in,
                              void* d_out, int out_size, void* d_ws, size_t ws_size,
                              hipStream_t stream) {
    const float* x     = (const float*)d_in[0];
    const float* wsq   = (const float*)d_in[1];
    const float* bsq   = (const float*)d_in[2];
    const float* gamma = (const float*)d_in[3];
    const float* beta  = (const float*)d_in[4];
    const float* rmean = (const float*)d_in[5];
    const float* rvar  = (const float*)d_in[6];
    const float* wc1   = (const float*)d_in[7];
    const float* bc1   = (const float*)d_in[8];
    const float* wex   = (const float*)d_in[9];
    const float* bex   = (const float*)d_in[10];

    k_pipe<<<512, 256, 0, stream>>>(x, wsq, bsq, gamma, beta,
                                    rmean, rvar, wc1, bc1, wex, bex,
                                    (float*)d_out);
}